// Round 2
// baseline (342.909 us; speedup 1.0000x reference)
//
#include <hip/hip_runtime.h>

// RoleSensitiveEmbedding: out[t,:] = W_{role[t]} @ emb[ids[t],:]
// Partition tokens by role (atomic two-sided packing) -> bf16 MFMA GEMM per
// region (half the FLOPs of reference's compute-both-and-select).
// R2: 256x128 GEMM tile (A-frags read once/wave, 64 MFMA per barrier),
//     wconv fused into gather, k_init replaced by hipMemsetAsync.

#define M_TOK   16384
#define DIM     1024
#define MT      256                 // gemm m-tile rows
#define NTIL    65                  // ceil(n0/256)+ceil(n1/256) <= 65 always
#define XROWS   (NTIL * MT)         // 16640
#define BK      64
#define WBLKS   2048                // 2*1024*1024 floats / (256 thr * 4)

typedef __attribute__((ext_vector_type(8))) short short8;
typedef __attribute__((ext_vector_type(4))) float f32x4;

// ---- workspace layout (bytes) ----
#define OFF_PERM 256
#define OFF_WB   66816
#define OFF_X    4261120
// total ~38.3 MB

static __device__ __forceinline__ unsigned short f2bf(float f) {
    unsigned int u = __float_as_uint(f);
    u += 0x7fffu + ((u >> 16) & 1u);   // round-to-nearest-even
    return (unsigned short)(u >> 16);
}

__global__ void k_perm(const int* __restrict__ role, int* perm, int* cnt) {
    int t = blockIdx.x * 256 + threadIdx.x;   // 0..16383
    int row;
    if (role[t] == 1) { int s = atomicAdd(&cnt[1], 1); row = XROWS - 1 - s; }
    else              { int s = atomicAdd(&cnt[0], 1); row = s; }
    perm[row] = t;
}

// blocks [0,XROWS): gather emb[ids[perm[row]]] -> bf16 X[row]
// blocks [XROWS, XROWS+WBLKS): convert W0|W1 fp32 -> bf16 Wb
__global__ void k_fused(const int* __restrict__ ids, const int* __restrict__ perm,
                        const float* __restrict__ emb,
                        const float* __restrict__ W0, const float* __restrict__ W1,
                        unsigned short* __restrict__ X, unsigned short* __restrict__ Wb) {
    int b = blockIdx.x;
    int t = threadIdx.x;
    if (b < XROWS) {
        int p = perm[b];
        if (p < 0) return;                 // gap row: leave poison (outputs skipped)
        int id = ids[p];
        float4 f = *(const float4*)(emb + (size_t)id * DIM + t * 4);
        ushort4 v = make_ushort4(f2bf(f.x), f2bf(f.y), f2bf(f.z), f2bf(f.w));
        *(ushort4*)(X + (size_t)b * DIM + t * 4) = v;
    } else {
        int idx = ((b - XROWS) * 256 + t) * 4;         // 0 .. 2*1048576-4
        const float* src = (idx < 1048576) ? (W0 + idx) : (W1 + (idx - 1048576));
        float4 f = *(const float4*)src;
        ushort4 v = make_ushort4(f2bf(f.x), f2bf(f.y), f2bf(f.z), f2bf(f.w));
        *(ushort4*)(Wb + idx) = v;
    }
}

// 256x128 tile GEMM, C = A * B^T: A = X[XROWS,1024] bf16, B^T = W_e rows.
// 4 waves stacked on M (64 rows each), all cover the 128 N-cols.
// LDS staged via global_load_lds width=16, XOR swizzle kc^(row&7) on the
// global-gather side so ds_read_b128 fragment reads stay ~conflict-free.
__global__ __launch_bounds__(256, 2)
void k_gemm(const unsigned short* __restrict__ Xu, const unsigned short* __restrict__ Wbu,
            const int* __restrict__ perm, const int* __restrict__ cnt,
            float* __restrict__ out) {
    __shared__ short As[MT * BK];      // 32 KB
    __shared__ short Bs[128 * BK];     // 16 KB

    // XCD swizzle: all 8 n-tiles of an m-tile share one XCD's L2 (A read once/XCD)
    int f  = blockIdx.x;
    int mt = ((f >> 6) << 3) | (f & 7);
    int nt = (f >> 3) & 7;
    if (mt >= NTIL) return;

    int n0 = cnt[0], n1 = cnt[1];
    int T0 = (n0 + 255) >> 8, T1 = (n1 + 255) >> 8;
    int e;
    if (mt < T0)              e = 0;       // bottom region: role 0
    else if (mt >= NTIL - T1) e = 1;       // top region: role 1
    else return;                           // gap tile

    const short* Ag = (const short*)Xu + (size_t)mt * MT * DIM;
    const short* Bg = (const short*)Wbu + (size_t)e * DIM * DIM + (size_t)nt * 128 * DIM;

    int tid  = threadIdx.x;
    int lane = tid & 63;
    int w    = tid >> 6;                 // wave 0..3 = M-slice
    int quad = lane >> 4, lq = lane & 15;

    f32x4 acc[4][8] = {};

    for (int k0 = 0; k0 < DIM; k0 += BK) {
#pragma unroll
        for (int q = 0; q < 8; ++q) {    // A: 2048 16B slots
            int s   = q * 256 + tid;
            int row = s >> 3;
            int kc  = (s & 7) ^ (row & 7);
            __builtin_amdgcn_global_load_lds(
                (const __attribute__((address_space(1))) unsigned int*)(Ag + (size_t)row * DIM + k0 + kc * 8),
                (__attribute__((address_space(3))) unsigned int*)(&As[s * 8]),
                16, 0, 0);
        }
#pragma unroll
        for (int q = 0; q < 4; ++q) {    // B: 1024 16B slots
            int s   = q * 256 + tid;
            int row = s >> 3;
            int kc  = (s & 7) ^ (row & 7);
            __builtin_amdgcn_global_load_lds(
                (const __attribute__((address_space(1))) unsigned int*)(Bg + (size_t)row * DIM + k0 + kc * 8),
                (__attribute__((address_space(3))) unsigned int*)(&Bs[s * 8]),
                16, 0, 0);
        }
        __syncthreads();

#pragma unroll
        for (int s = 0; s < 2; ++s) {
            int s4q = s * 4 + quad;
            short8 av[4];
#pragma unroll
            for (int i = 0; i < 4; ++i) {
                int ra = w * 64 + i * 16 + lq;
                av[i] = *(const short8*)&As[(ra * 8 + (s4q ^ (ra & 7))) * 8];
            }
#pragma unroll
            for (int jh = 0; jh < 2; ++jh) {
                short8 bv[4];
#pragma unroll
                for (int j = 0; j < 4; ++j) {
                    int rb = jh * 64 + j * 16 + lq;
                    bv[j] = *(const short8*)&Bs[(rb * 8 + (s4q ^ (rb & 7))) * 8];
                }
#pragma unroll
                for (int i = 0; i < 4; ++i)
#pragma unroll
                    for (int j = 0; j < 4; ++j)
                        acc[i][jh * 4 + j] = __builtin_amdgcn_mfma_f32_16x16x32_bf16(
                            av[i], bv[j], acc[i][jh * 4 + j], 0, 0, 0);
            }
        }
        __syncthreads();
    }

    // epilogue: C/D map m = quad*4+reg, n = lq; scatter rows to out[token,:]
    int colbase = nt * 128 + lq;
#pragma unroll
    for (int i = 0; i < 4; ++i) {
#pragma unroll
        for (int r = 0; r < 4; ++r) {
            int mrow  = mt * MT + w * 64 + i * 16 + quad * 4 + r;
            int token = perm[mrow];
            if (token < 0) continue;
            float* o = out + (size_t)token * DIM + colbase;
#pragma unroll
            for (int j = 0; j < 8; ++j)
                o[j * 16] = acc[i][j][r];
        }
    }
}

extern "C" void kernel_launch(void* const* d_in, const int* in_sizes, int n_in,
                              void* d_out, int out_size, void* d_ws, size_t ws_size,
                              hipStream_t stream) {
    const int*   ids  = (const int*)d_in[0];
    const int*   role = (const int*)d_in[1];
    const float* emb  = (const float*)d_in[2];
    const float* W0   = (const float*)d_in[3];
    const float* W1   = (const float*)d_in[4];
    float*       out  = (float*)d_out;

    char* ws = (char*)d_ws;
    int* cnt  = (int*)ws;
    int* perm = (int*)(ws + OFF_PERM);
    unsigned short* Wb = (unsigned short*)(ws + OFF_WB);
    unsigned short* X  = (unsigned short*)(ws + OFF_X);

    hipMemsetAsync(cnt,  0x00, 2 * sizeof(int),     stream);
    hipMemsetAsync(perm, 0xFF, XROWS * sizeof(int), stream);
    k_perm <<<M_TOK / 256,   256, 0, stream>>>(role, perm, cnt);
    k_fused<<<XROWS + WBLKS, 256, 0, stream>>>(ids, perm, emb, W0, W1, X, Wb);
    k_gemm <<<576,           256, 0, stream>>>(X, Wb, perm, cnt, out);
}

// Round 3
// 331.170 us; speedup vs baseline: 1.0354x; 1.0354x over previous
//
#include <hip/hip_runtime.h>

// RoleSensitiveEmbedding: out[t,:] = W_{role[t]} @ emb[ids[t],:]
// Partition tokens by role (atomic two-sided packing) -> bf16 MFMA GEMM per
// region (half the FLOPs of reference's compute-both-and-select).
// R3: back to 128x128 GEMM tile (m97-proven; R2's 256x128 was neutral/worse),
//     __launch_bounds__(256,3) for 3 blocks/CU, cnt-based validity (no perm
//     memset), wconv+perm fused into one pre-kernel. 1 memset + 3 kernels.

#define M_TOK   16384
#define DIM     1024
#define MT      128                 // gemm m-tile rows
#define NTIL    130                 // ceil(n0/128)+ceil(n1/128) <= 130 always
#define XROWS   (NTIL * MT)         // 16640
#define BK      64
#define PBLK    64                  // perm blocks (64*256 = 16384 tokens)
#define WBLKS   2048                // 2*1024*1024 floats / (256 thr * 4)

typedef __attribute__((ext_vector_type(8))) short short8;
typedef __attribute__((ext_vector_type(4))) float f32x4;

// ---- workspace layout (bytes) ----
#define OFF_PERM 256
#define OFF_WB   66816
#define OFF_X    4261120
// total ~38.3 MB

static __device__ __forceinline__ unsigned short f2bf(float f) {
    unsigned int u = __float_as_uint(f);
    u += 0x7fffu + ((u >> 16) & 1u);   // round-to-nearest-even
    return (unsigned short)(u >> 16);
}

// blocks [0,PBLK): role partition via two-sided atomic packing
// blocks [PBLK, PBLK+WBLKS): convert W0|W1 fp32 -> bf16 Wb
__global__ void k_pre(const int* __restrict__ role, int* perm, int* cnt,
                      const float* __restrict__ W0, const float* __restrict__ W1,
                      unsigned short* __restrict__ Wb) {
    int b = blockIdx.x;
    if (b < PBLK) {
        int t = b * 256 + threadIdx.x;           // 0..16383
        int row;
        if (role[t] == 1) { int s = atomicAdd(&cnt[1], 1); row = XROWS - 1 - s; }
        else              { int s = atomicAdd(&cnt[0], 1); row = s; }
        perm[row] = t;
    } else {
        int idx = ((b - PBLK) * 256 + threadIdx.x) * 4;   // 0 .. 2*1048576-4
        const float* src = (idx < 1048576) ? (W0 + idx) : (W1 + (idx - 1048576));
        float4 f = *(const float4*)src;
        *(ushort4*)(Wb + idx) = make_ushort4(f2bf(f.x), f2bf(f.y), f2bf(f.z), f2bf(f.w));
    }
}

// one block per staged row: gather emb[ids[perm[row]]] -> bf16 X[row]
// validity decided by cnt bounds (gap rows untouched; GEMM skips them too)
__global__ void k_gather(const int* __restrict__ ids, const int* __restrict__ perm,
                         const int* __restrict__ cnt, const float* __restrict__ emb,
                         unsigned short* __restrict__ X) {
    int b = blockIdx.x;
    int n0 = cnt[0], n1 = cnt[1];
    if (b >= n0 && b < XROWS - n1) return;       // gap row
    int p = perm[b];
    int id = ids[p];
    int t = threadIdx.x;
    float4 f = *(const float4*)(emb + (size_t)id * DIM + t * 4);
    *(ushort4*)(X + (size_t)b * DIM + t * 4) =
        make_ushort4(f2bf(f.x), f2bf(f.y), f2bf(f.z), f2bf(f.w));
}

// 128x128 tile GEMM, C = A * B^T: A = X[XROWS,1024] bf16, B^T = W_e rows.
// LDS staged via global_load_lds width=16, XOR swizzle kc^(row&7) on the
// global-gather side so ds_read_b128 fragment reads stay ~conflict-free.
__global__ __launch_bounds__(256, 3)
void k_gemm(const unsigned short* __restrict__ Xu, const unsigned short* __restrict__ Wbu,
            const int* __restrict__ perm, const int* __restrict__ cnt,
            float* __restrict__ out) {
    __shared__ short As[MT * BK];      // 16 KB
    __shared__ short Bs[MT * BK];      // 16 KB

    // XCD swizzle: all 8 n-tiles of an m-tile share one XCD's L2
    int f  = blockIdx.x;
    int mt = ((f >> 6) << 3) | (f & 7);
    int nt = (f >> 3) & 7;
    if (mt >= NTIL) return;

    int n0 = cnt[0], n1 = cnt[1];
    int T0 = (n0 + 127) >> 7, T1 = (n1 + 127) >> 7;
    int e, lo, hi;
    if (mt < T0)              { e = 0; lo = 0;            hi = n0;    }
    else if (mt >= NTIL - T1) { e = 1; lo = XROWS - n1;   hi = XROWS; }
    else return;                           // gap tile

    const short* Ag = (const short*)Xu + (size_t)mt * MT * DIM;
    const short* Bg = (const short*)Wbu + (size_t)e * DIM * DIM + (size_t)nt * MT * DIM;

    int tid  = threadIdx.x;
    int lane = tid & 63;
    int w    = tid >> 6;         // wave 0..3
    int wm   = w & 1, wn = w >> 1;
    int quad = lane >> 4, lq = lane & 15;

    f32x4 acc[4][4] = {};

    for (int k0 = 0; k0 < DIM; k0 += BK) {
#pragma unroll
        for (int i = 0; i < 4; ++i) {
            int q   = w * 4 + i;          // wave-uniform issue id 0..15
            int s   = q * 64 + lane;      // 16B slot index in tile
            int row = s >> 3;
            int kc  = (s & 7) ^ (row & 7);   // swizzled source k-chunk
            __builtin_amdgcn_global_load_lds(
                (const __attribute__((address_space(1))) unsigned int*)(Ag + (size_t)row * DIM + k0 + kc * 8),
                (__attribute__((address_space(3))) unsigned int*)(&As[s * 8]),
                16, 0, 0);
            __builtin_amdgcn_global_load_lds(
                (const __attribute__((address_space(1))) unsigned int*)(Bg + (size_t)row * DIM + k0 + kc * 8),
                (__attribute__((address_space(3))) unsigned int*)(&Bs[s * 8]),
                16, 0, 0);
        }
        __syncthreads();

#pragma unroll
        for (int s = 0; s < 2; ++s) {
            short8 av[4], bv[4];
            int s4q = s * 4 + quad;
#pragma unroll
            for (int i = 0; i < 4; ++i) {
                int ra = wm * 64 + i * 16 + lq;
                av[i] = *(const short8*)&As[(ra * 8 + (s4q ^ (ra & 7))) * 8];
                int rb = wn * 64 + i * 16 + lq;
                bv[i] = *(const short8*)&Bs[(rb * 8 + (s4q ^ (rb & 7))) * 8];
            }
#pragma unroll
            for (int i = 0; i < 4; ++i)
#pragma unroll
                for (int j = 0; j < 4; ++j)
                    acc[i][j] = __builtin_amdgcn_mfma_f32_16x16x32_bf16(
                        av[i], bv[j], acc[i][j], 0, 0, 0);
        }
        __syncthreads();
    }

    // epilogue: C/D map m = quad*4+reg, n = lq; scatter rows to out[token,:]
    int colbase = nt * 128 + wn * 64 + lq;
#pragma unroll
    for (int i = 0; i < 4; ++i) {
#pragma unroll
        for (int r = 0; r < 4; ++r) {
            int mrow = mt * MT + wm * 64 + i * 16 + quad * 4 + r;
            if (mrow < lo || mrow >= hi) continue;   // gap row (bounds, not sentinel)
            int token = perm[mrow];
            float* o = out + (size_t)token * DIM + colbase;
#pragma unroll
            for (int j = 0; j < 4; ++j)
                o[j * 16] = acc[i][j][r];
        }
    }
}

extern "C" void kernel_launch(void* const* d_in, const int* in_sizes, int n_in,
                              void* d_out, int out_size, void* d_ws, size_t ws_size,
                              hipStream_t stream) {
    const int*   ids  = (const int*)d_in[0];
    const int*   role = (const int*)d_in[1];
    const float* emb  = (const float*)d_in[2];
    const float* W0   = (const float*)d_in[3];
    const float* W1   = (const float*)d_in[4];
    float*       out  = (float*)d_out;

    char* ws = (char*)d_ws;
    int* cnt  = (int*)ws;
    int* perm = (int*)(ws + OFF_PERM);
    unsigned short* Wb = (unsigned short*)(ws + OFF_WB);
    unsigned short* X  = (unsigned short*)(ws + OFF_X);

    hipMemsetAsync(cnt, 0x00, 2 * sizeof(int), stream);
    k_pre   <<<PBLK + WBLKS, 256, 0, stream>>>(role, perm, cnt, W0, W1, Wb);
    k_gather<<<XROWS,        256, 0, stream>>>(ids, perm, cnt, emb, X);
    k_gemm  <<<1088,         256, 0, stream>>>(X, Wb, perm, cnt, out);
}